// Round 7
// baseline (143.324 us; speedup 1.0000x reference)
//
#include <hip/hip_runtime.h>
#include <math.h>

#define T_ 30
#define C_ 512
#define N_ 784      // 28*28; k_assign: 25 tiles of 32 (last half-valid)
#define NA_ 800     // aT row pitch (25 ksteps of 32)
#define SPITCH 72   // per-wave stage row pitch (ushorts) for one 64-c half
#define EPSV 1e-12f

typedef __attribute__((ext_vector_type(8))) short bf16x8;
typedef __attribute__((ext_vector_type(4))) float f32x4;

__device__ __forceinline__ unsigned short f2bf(float f) {
    union { float f; unsigned int u; } v; v.f = f;
    unsigned int r = (v.u + 0x7FFFu + ((v.u >> 16) & 1u)) >> 16;  // RNE
    return (unsigned short)r;
}
__device__ __forceinline__ float bf2f(unsigned short h) {
    union { unsigned int u; float f; } v; v.u = ((unsigned int)h) << 16;
    return v.f;
}

// wh/wl: split-precision bf16 of w, layout [k][c]
__global__ void k_prep(const float* __restrict__ w, unsigned short* __restrict__ wh,
                       unsigned short* __restrict__ wl) {
    int idx = blockIdx.x * 256 + threadIdx.x;  // 0..32767
    float v = w[idx];
    unsigned short h = f2bf(v);
    wh[idx] = h;
    wl[idx] = f2bf(v - bf2f(h));
}

// Fused invnorm + logits (3-product split-bf16 MFMA) + softmax + aT + asum.
// v7: 32-n tiles, grid (25, 30). Each wave-load now covers 128 B contiguous
// per c-row (8 lanes x 16 B) instead of 64 B -> half the cache-line requests
// per byte (MSHR-limit theory). Block 24 upper rows (n=784..799) are invalid
// and store zeros = the aT tail. LDS 37.4 KB -> 4 blocks/CU >= 2.9 needed.
__global__ __launch_bounds__(256, 4) void k_assign(
    const float* __restrict__ x, const unsigned short* __restrict__ wh,
    const unsigned short* __restrict__ wl, const float* __restrict__ b,
    unsigned short* __restrict__ aT, float* __restrict__ asum)
{
    // stage: xh/xl [4 w][32 n][SPITCH] ushort (one 64-c half per wave at a time)
    // red (union, reused after MFMA): [4 w][32 n][68 k] f32 = 34816 B
    __shared__ __align__(16) char smem[2 * 4 * 32 * SPITCH * 2];  // 36864 B
    unsigned short* xh = (unsigned short*)smem;
    unsigned short* xl = xh + 4 * 32 * SPITCH;
    float* red = (float*)smem;
    __shared__ float ssq[4][32];

    int t = blockIdx.y, n0 = blockIdx.x * 32;
    int tid = threadIdx.x;
    int w = tid >> 6, L = tid & 63, lid = L & 15, quad = L >> 4;
    int cbase = w * 128;            // wave-private c-slice [cbase, cbase+128)
    int nseg = (L & 7) * 4;         // n offset 0/4/.../28
    int crow = L >> 3;              // 0..7

    int ncol = n0 + nseg;
    if (ncol > 780) ncol = 780;     // block 24 clamp (invalid rows unstored)
    const float* xb = x + (size_t)t * C_ * N_ + ncol;
    unsigned short* shh = xh + w * 32 * SPITCH;
    unsigned short* shl = xl + w * 32 * SPITCH;
    const unsigned short* wha = wh + (size_t)lid * C_ + cbase + quad * 8;
    const unsigned short* wla = wl + (size_t)lid * C_ + cbase + quad * 8;

    float bk = b[L];
    float ss0 = 0.f, ss1 = 0.f, ss2 = 0.f, ss3 = 0.f;
    f32x4 acc[4][2];
    #pragma unroll
    for (int mt = 0; mt < 4; ++mt)
        #pragma unroll
        for (int nt = 0; nt < 2; ++nt)
            #pragma unroll
            for (int r = 0; r < 4; ++r) acc[mt][nt][r] = 0.f;

    #pragma unroll
    for (int half = 0; half < 2; ++half) {
        // 8 loads in flight: 8 c-rows/pass x 8 passes = 64 c rows, 32 n wide
        float4 q[8];
        #pragma unroll
        for (int p = 0; p < 8; ++p)
            q[p] = *reinterpret_cast<const float4*>(
                xb + (size_t)(cbase + half * 64 + p * 8 + crow) * N_);
        // stage (transpose + hi/lo split), accumulate sumsq
        #pragma unroll
        for (int p = 0; p < 8; ++p) {
            int cl = p * 8 + crow;             // 0..63 within stage
            float vv[4] = {q[p].x, q[p].y, q[p].z, q[p].w};
            ss0 = fmaf(vv[0], vv[0], ss0); ss1 = fmaf(vv[1], vv[1], ss1);
            ss2 = fmaf(vv[2], vv[2], ss2); ss3 = fmaf(vv[3], vv[3], ss3);
            #pragma unroll
            for (int j = 0; j < 4; ++j) {
                unsigned short h = f2bf(vv[j]);
                shh[(nseg + j) * SPITCH + cl] = h;
                shl[(nseg + j) * SPITCH + cl] = f2bf(vv[j] - bf2f(h));
            }
        }
        // MFMA over this half (reads only this wave's own stage rows)
        #pragma unroll
        for (int ks2 = 0; ks2 < 2; ++ks2) {
            int so = ks2 * 32 + quad * 8;
            bf16x8 bh0 = *reinterpret_cast<const bf16x8*>(&shh[lid * SPITCH + so]);
            bf16x8 bl0 = *reinterpret_cast<const bf16x8*>(&shl[lid * SPITCH + so]);
            bf16x8 bh1 = *reinterpret_cast<const bf16x8*>(&shh[(16 + lid) * SPITCH + so]);
            bf16x8 bl1 = *reinterpret_cast<const bf16x8*>(&shl[(16 + lid) * SPITCH + so]);
            int cg = half * 64 + ks2 * 32;
            #pragma unroll
            for (int mt = 0; mt < 4; ++mt) {
                bf16x8 ah = *reinterpret_cast<const bf16x8*>(
                    wha + (size_t)mt * 16 * C_ + cg);
                bf16x8 al = *reinterpret_cast<const bf16x8*>(
                    wla + (size_t)mt * 16 * C_ + cg);
                acc[mt][0] = __builtin_amdgcn_mfma_f32_16x16x32_bf16(ah, bh0, acc[mt][0], 0, 0, 0);
                acc[mt][0] = __builtin_amdgcn_mfma_f32_16x16x32_bf16(al, bh0, acc[mt][0], 0, 0, 0);
                acc[mt][0] = __builtin_amdgcn_mfma_f32_16x16x32_bf16(ah, bl0, acc[mt][0], 0, 0, 0);
                acc[mt][1] = __builtin_amdgcn_mfma_f32_16x16x32_bf16(ah, bh1, acc[mt][1], 0, 0, 0);
                acc[mt][1] = __builtin_amdgcn_mfma_f32_16x16x32_bf16(al, bh1, acc[mt][1], 0, 0, 0);
                acc[mt][1] = __builtin_amdgcn_mfma_f32_16x16x32_bf16(ah, bl1, acc[mt][1], 0, 0, 0);
            }
        }
    }
    // reduce sumsq over same-nseg lanes (stride-8 within wave)
    #pragma unroll
    for (int m = 8; m <= 32; m <<= 1) {
        ss0 += __shfl_xor(ss0, m, 64); ss1 += __shfl_xor(ss1, m, 64);
        ss2 += __shfl_xor(ss2, m, 64); ss3 += __shfl_xor(ss3, m, 64);
    }
    if (L < 8) {
        ssq[w][L * 4 + 0] = ss0; ssq[w][L * 4 + 1] = ss1;
        ssq[w][L * 4 + 2] = ss2; ssq[w][L * 4 + 3] = ss3;
    }
    __syncthreads();   // all waves done with stage -> reuse as red
    {
        float* rp = red + w * (32 * 68);
        #pragma unroll
        for (int mt = 0; mt < 4; ++mt)
            #pragma unroll
            for (int nt = 0; nt < 2; ++nt)
                *reinterpret_cast<f32x4*>(
                    &rp[(nt * 16 + lid) * 68 + mt * 16 + quad * 4]) = acc[mt][nt];
    }
    __syncthreads();

    // ---- softmax: wave w handles n rows w*8..w*8+7; lane L = k (lockstep rows)
    float vv[8], iv[8];
    #pragma unroll
    for (int i = 0; i < 8; ++i) {
        int n = w * 8 + i;
        float s = ssq[0][n] + ssq[1][n] + ssq[2][n] + ssq[3][n];
        iv[i] = 1.0f / fmaxf(sqrtf(s), EPSV);
        float v = red[0 * 2176 + n * 68 + L] + red[1 * 2176 + n * 68 + L]
                + red[2 * 2176 + n * 68 + L] + red[3 * 2176 + n * 68 + L];
        vv[i] = fmaf(v, iv[i], bk);
    }
    float mx[8];
    #pragma unroll
    for (int i = 0; i < 8; ++i) mx[i] = vv[i];
    #pragma unroll
    for (int m = 1; m <= 32; m <<= 1) {
        #pragma unroll
        for (int i = 0; i < 8; ++i) mx[i] = fmaxf(mx[i], __shfl_xor(mx[i], m, 64));
    }
    float e[8], se[8];
    #pragma unroll
    for (int i = 0; i < 8; ++i) { e[i] = __expf(vv[i] - mx[i]); se[i] = e[i]; }
    #pragma unroll
    for (int m = 1; m <= 32; m <<= 1) {
        #pragma unroll
        for (int i = 0; i < 8; ++i) se[i] += __shfl_xor(se[i], m, 64);
    }
    float asl = 0.f;
    unsigned short av[8];
    #pragma unroll
    for (int i = 0; i < 8; ++i) {
        bool valid = (n0 + w * 8 + i) < N_;   // block 24, w>=2: zero-fill = aT tail
        float a = e[i] / se[i];
        av[i] = valid ? f2bf(a * iv[i]) : (unsigned short)0;
        asl += valid ? a : 0.f;
    }
    atomicAdd(&asum[t * 64 + L], asl);
    unsigned short* dst = aT + ((size_t)t * 64 + L) * NA_ + n0 + w * 8;
    ushort4 s0; s0.x = av[0]; s0.y = av[1]; s0.z = av[2]; s0.w = av[3];
    ushort4 s1; s1.x = av[4]; s1.y = av[5]; s1.z = av[6]; s1.w = av[7];
    *reinterpret_cast<ushort4*>(dst) = s0;
    *reinterpret_cast<ushort4*>(dst + 4) = s1;
}

// vlad[t][k][c] = sum_n ahat[k][n]*x[c][n] - asum[k]*cent[k][c]; g2 partial fused.
// split over k-halves (grid 32 x 2 x 30 = 1920 blocks, 7.5/CU):
// disjoint vlad stores (no atomics), per-block 2 MFMA tiles; x fp32 (L3-hot).
__global__ __launch_bounds__(256, 4) void k_vlad(
    const float* __restrict__ x, const unsigned short* __restrict__ aT,
    const float* __restrict__ asum, const float* __restrict__ cent,
    float* __restrict__ vlad, float* __restrict__ g2)
{
    __shared__ float red[4][16 * 36];   // [wave][c(16) x k(32)+pad4]
    int t = blockIdx.z, kh = blockIdx.y, c0 = blockIdx.x * 16;
    int tid = threadIdx.x;
    int w = tid >> 6, L = tid & 63, lid = L & 15, quad = L >> 4;

    f32x4 acc[2];
    #pragma unroll
    for (int mt = 0; mt < 2; ++mt)
        #pragma unroll
        for (int r = 0; r < 4; ++r) acc[mt][r] = 0.f;

    const float* xrow = x + ((size_t)t * C_ + c0 + lid) * N_;
    const unsigned short* a0 = aT + ((size_t)t * 64 + kh * 32 + lid) * NA_;

    // epilogue operands issued early: thread -> (k_loc, 2 c's)
    int k_loc = tid >> 3, j8 = tid & 7, ce = j8 * 2;
    int kg = kh * 32 + k_loc;
    float as = asum[t * 64 + kg];
    float2 cv = *reinterpret_cast<const float2*>(cent + kg * C_ + c0 + ce);

    // prologue: load step s0 = w
    int nb = w * 32 + quad * 8;
    int nc = nb > 776 ? 776 : nb;   // clamped lanes hit aT zeros
    float4 x0c = *reinterpret_cast<const float4*>(xrow + nc);
    float4 x1c = *reinterpret_cast<const float4*>(xrow + nc + 4);
    bf16x8 f0 = *reinterpret_cast<const bf16x8*>(a0 + nb);
    bf16x8 f1 = *reinterpret_cast<const bf16x8*>(a0 + 16 * NA_ + nb);

    for (int s = w; s < 25; s += 4) {
        int sn = s + 4;
        float4 x0n = x0c, x1n = x1c;
        bf16x8 g0 = f0, g1 = f1;
        if (sn < 25) {  // wave-uniform: prefetch next step
            int nb2 = sn * 32 + quad * 8;
            int nc2 = nb2 > 776 ? 776 : nb2;
            x0n = *reinterpret_cast<const float4*>(xrow + nc2);
            x1n = *reinterpret_cast<const float4*>(xrow + nc2 + 4);
            g0  = *reinterpret_cast<const bf16x8*>(a0 + nb2);
            g1  = *reinterpret_cast<const bf16x8*>(a0 + 16 * NA_ + nb2);
        }
        bf16x8 bb;
        bb[0] = (short)f2bf(x0c.x); bb[1] = (short)f2bf(x0c.y);
        bb[2] = (short)f2bf(x0c.z); bb[3] = (short)f2bf(x0c.w);
        bb[4] = (short)f2bf(x1c.x); bb[5] = (short)f2bf(x1c.y);
        bb[6] = (short)f2bf(x1c.z); bb[7] = (short)f2bf(x1c.w);
        acc[0] = __builtin_amdgcn_mfma_f32_16x16x32_bf16(f0, bb, acc[0], 0, 0, 0);
        acc[1] = __builtin_amdgcn_mfma_f32_16x16x32_bf16(f1, bb, acc[1], 0, 0, 0);
        x0c = x0n; x1c = x1n; f0 = g0; f1 = g1;
    }
    {
        float* rp = &red[w][0];
        #pragma unroll
        for (int mt = 0; mt < 2; ++mt)
            *reinterpret_cast<f32x4*>(&rp[lid * 36 + mt * 16 + quad * 4]) = acc[mt];
    }
    __syncthreads();

    // epilogue: v for (kg, ce..ce+1); fused g2 partial
    float2 vout;
    float s2 = 0.f;
    #pragma unroll
    for (int j = 0; j < 2; ++j) {
        int cc = ce + j;
        float v = red[0][cc * 36 + k_loc] + red[1][cc * 36 + k_loc]
                + red[2][cc * 36 + k_loc] + red[3][cc * 36 + k_loc];
        v -= as * ((const float*)&cv)[j];
        ((float*)&vout)[j] = v;
        s2 = fmaf(v, v, s2);
    }
    *reinterpret_cast<float2*>(vlad + ((size_t)t * 64 + kg) * C_ + c0 + ce) = vout;
    s2 += __shfl_xor(s2, 1, 64);
    s2 += __shfl_xor(s2, 2, 64);
    s2 += __shfl_xor(s2, 4, 64);
    if (j8 == 0) atomicAdd(&g2[t * 64 + kg], s2);
}

// out[k*512+c] = sum_t vlad * inv_intra * inv_g. t split over 2 thread-halves
// (grid 256 blocks, 128 idx each) for 2x parallelism + half-depth load chains.
__global__ __launch_bounds__(256) void k_out(
    const float* __restrict__ vlad, const float* __restrict__ g2,
    float* __restrict__ out)
{
    __shared__ float intr[1920];
    __shared__ float gl[1920];
    __shared__ float sinv[T_];
    __shared__ float part[256];
    int tid = threadIdx.x;
    for (int i = tid; i < 1920; i += 256) {
        float s = g2[i];
        gl[i] = s;
        intr[i] = 1.0f / fmaxf(sqrtf(s), EPSV);
    }
    __syncthreads();
    if (tid < T_) {
        float s = 0.f;
        #pragma unroll 8
        for (int k = 0; k < 64; ++k) {
            float iv = intr[tid * 64 + k];
            s += gl[tid * 64 + k] * iv * iv;
        }
        sinv[tid] = 1.0f / fmaxf(sqrtf(s), EPSV);
    }
    __syncthreads();
    int idx = blockIdx.x * 128 + (tid & 127);  // k*512+c
    int th = tid >> 7;
    int k = idx >> 9;
    float s = 0.f;
    #pragma unroll
    for (int t = th * 15; t < th * 15 + 15; ++t)
        s += vlad[(size_t)t * 32768 + idx] * intr[t * 64 + k] * sinv[t];
    part[tid] = s;
    __syncthreads();
    if (tid < 128) out[idx] = part[tid] + part[tid + 128];
}

extern "C" void kernel_launch(void* const* d_in, const int* in_sizes, int n_in,
                              void* d_out, int out_size, void* d_ws, size_t ws_size,
                              hipStream_t stream) {
    const float* x    = (const float*)d_in[0];   // 30*512*784
    const float* cent = (const float*)d_in[1];   // 64*512
    const float* w    = (const float*)d_in[2];   // 64*512
    const float* b    = (const float*)d_in[3];   // 64
    float* out = (float*)d_out;

    char* p = (char*)d_ws;
    unsigned short* wh = (unsigned short*)p;  p += 65536;
    unsigned short* wl = (unsigned short*)p;  p += 65536;
    float* asum = (float*)p;                  p += 1920 * 4;
    float* g2   = (float*)p;                  p += 1920 * 4;
    float* vlad = (float*)p;                  p += (size_t)T_ * 64 * C_ * 4;   // 3,932,160
    unsigned short* aT = (unsigned short*)p;  p += (size_t)T_ * 64 * NA_ * 2;  // 3,072,000
    // total ~= 7.2 MB

    k_prep<<<128, 256, 0, stream>>>(w, wh, wl);
    hipMemsetAsync(asum, 0, 2 * 1920 * 4, stream);   // asum + g2 (15 KB only)
    k_assign<<<dim3(25, T_), 256, 0, stream>>>(x, wh, wl, b, aT, asum);
    k_vlad<<<dim3(32, 2, T_), 256, 0, stream>>>(x, aT, asum, cent, vlad, g2);
    k_out<<<256, 256, 0, stream>>>(vlad, g2, out);
}

// Round 8
// 129.758 us; speedup vs baseline: 1.1045x; 1.1045x over previous
//
#include <hip/hip_runtime.h>
#include <math.h>

#define T_ 30
#define C_ 512
#define N_ 784      // 28*28; k_assign: 25 tiles of 32 (last half-valid)
#define NA_ 800     // aT row pitch (25 ksteps of 32)
#define QP 36       // per-wave stage row pitch (ushorts) for one 32-c quarter
#define EPSV 1e-12f

typedef __attribute__((ext_vector_type(8))) short bf16x8;
typedef __attribute__((ext_vector_type(4))) float f32x4;

__device__ __forceinline__ unsigned short f2bf(float f) {
    union { float f; unsigned int u; } v; v.f = f;
    unsigned int r = (v.u + 0x7FFFu + ((v.u >> 16) & 1u)) >> 16;  // RNE
    return (unsigned short)r;
}
__device__ __forceinline__ float bf2f(unsigned short h) {
    union { unsigned int u; float f; } v; v.u = ((unsigned int)h) << 16;
    return v.f;
}

// wh/wl: split-precision bf16 of w, layout [k][c]
__global__ void k_prep(const float* __restrict__ w, unsigned short* __restrict__ wh,
                       unsigned short* __restrict__ wl) {
    int idx = blockIdx.x * 256 + threadIdx.x;  // 0..32767
    float v = w[idx];
    unsigned short h = f2bf(v);
    wh[idx] = h;
    wl[idx] = f2bf(v - bf2f(h));
}

// Fused invnorm + logits (3-product split-bf16 MFMA) + softmax + aT + asum.
// v8: 32-n tile (128 B contiguous per c-row per load) with SPILL-FREE budget:
// one 32-c quarter staged per wave at a time (stage 18.4 KB, QP=36 -> 2-way
// banks), q[4] load batches, softmax in two 16-n phases over a 17.4 KB red.
// grid (25, 30). Block 24 rows n>=784 are invalid -> phase-B zeros = aT tail.
__global__ __launch_bounds__(256, 4) void k_assign(
    const float* __restrict__ x, const unsigned short* __restrict__ wh,
    const unsigned short* __restrict__ wl, const float* __restrict__ b,
    unsigned short* __restrict__ aT, float* __restrict__ asum)
{
    // stage: xh/xl [4 w][32 n][QP] ushort = 18432 B
    // red (union, after stage dead): [4 w][16 n][68 k] f32 = 17408 B
    __shared__ __align__(16) char smem[4 * 32 * QP * 2 * 2];  // 18432 B
    unsigned short* xh = (unsigned short*)smem;
    unsigned short* xl = xh + 4 * 32 * QP;
    float* red = (float*)smem;
    __shared__ float ssq[4][32];

    int t = blockIdx.y, n0 = blockIdx.x * 32;
    int tid = threadIdx.x;
    int w = tid >> 6, L = tid & 63, lid = L & 15, quad = L >> 4;
    int cbase = w * 128;            // wave-private c-slice [cbase, cbase+128)
    int nseg = (L & 7) * 4;         // n offset 0/4/.../28
    int crow = L >> 3;              // 0..7

    int ncol = n0 + nseg;
    if (ncol > 780) ncol = 780;     // block 24: invalid rows read real (wrong) data
    const float* xb = x + (size_t)t * C_ * N_ + ncol;
    unsigned short* shh = xh + w * 32 * QP;
    unsigned short* shl = xl + w * 32 * QP;
    const unsigned short* wha = wh + (size_t)lid * C_ + cbase + quad * 8;
    const unsigned short* wla = wl + (size_t)lid * C_ + cbase + quad * 8;

    float bk = b[L];
    float ss0 = 0.f, ss1 = 0.f, ss2 = 0.f, ss3 = 0.f;
    f32x4 acc[4][2];
    #pragma unroll
    for (int mt = 0; mt < 4; ++mt)
        #pragma unroll
        for (int nt = 0; nt < 2; ++nt)
            #pragma unroll
            for (int r = 0; r < 4; ++r) acc[mt][nt][r] = 0.f;

    #pragma unroll
    for (int qtr = 0; qtr < 4; ++qtr) {
        // 4 loads in flight: 8 c-rows each, 128 B contiguous per row
        float4 q[4];
        #pragma unroll
        for (int p = 0; p < 4; ++p)
            q[p] = *reinterpret_cast<const float4*>(
                xb + (size_t)(cbase + qtr * 32 + p * 8 + crow) * N_);
        // stage (transpose + hi/lo split), accumulate sumsq
        #pragma unroll
        for (int p = 0; p < 4; ++p) {
            int cl = p * 8 + crow;             // 0..31 within quarter
            float vv[4] = {q[p].x, q[p].y, q[p].z, q[p].w};
            ss0 = fmaf(vv[0], vv[0], ss0); ss1 = fmaf(vv[1], vv[1], ss1);
            ss2 = fmaf(vv[2], vv[2], ss2); ss3 = fmaf(vv[3], vv[3], ss3);
            #pragma unroll
            for (int j = 0; j < 4; ++j) {
                unsigned short h = f2bf(vv[j]);
                shh[(nseg + j) * QP + cl] = h;
                shl[(nseg + j) * QP + cl] = f2bf(vv[j] - bf2f(h));
            }
        }
        // MFMA: one 32-c k-step over this quarter (wave-private stage rows)
        int so = quad * 8;
        bf16x8 bh0 = *reinterpret_cast<const bf16x8*>(&shh[lid * QP + so]);
        bf16x8 bl0 = *reinterpret_cast<const bf16x8*>(&shl[lid * QP + so]);
        bf16x8 bh1 = *reinterpret_cast<const bf16x8*>(&shh[(16 + lid) * QP + so]);
        bf16x8 bl1 = *reinterpret_cast<const bf16x8*>(&shl[(16 + lid) * QP + so]);
        int cg = qtr * 32;
        #pragma unroll
        for (int mt = 0; mt < 4; ++mt) {
            bf16x8 ah = *reinterpret_cast<const bf16x8*>(
                wha + (size_t)mt * 16 * C_ + cg);
            bf16x8 al = *reinterpret_cast<const bf16x8*>(
                wla + (size_t)mt * 16 * C_ + cg);
            acc[mt][0] = __builtin_amdgcn_mfma_f32_16x16x32_bf16(ah, bh0, acc[mt][0], 0, 0, 0);
            acc[mt][0] = __builtin_amdgcn_mfma_f32_16x16x32_bf16(al, bh0, acc[mt][0], 0, 0, 0);
            acc[mt][0] = __builtin_amdgcn_mfma_f32_16x16x32_bf16(ah, bl0, acc[mt][0], 0, 0, 0);
            acc[mt][1] = __builtin_amdgcn_mfma_f32_16x16x32_bf16(ah, bh1, acc[mt][1], 0, 0, 0);
            acc[mt][1] = __builtin_amdgcn_mfma_f32_16x16x32_bf16(al, bh1, acc[mt][1], 0, 0, 0);
            acc[mt][1] = __builtin_amdgcn_mfma_f32_16x16x32_bf16(ah, bl1, acc[mt][1], 0, 0, 0);
        }
    }
    // reduce sumsq over lanes with same nseg (crow + upper strides)
    #pragma unroll
    for (int m = 8; m <= 32; m <<= 1) {
        ss0 += __shfl_xor(ss0, m, 64); ss1 += __shfl_xor(ss1, m, 64);
        ss2 += __shfl_xor(ss2, m, 64); ss3 += __shfl_xor(ss3, m, 64);
    }
    if (L < 8) {
        ssq[w][L * 4 + 0] = ss0; ssq[w][L * 4 + 1] = ss1;
        ssq[w][L * 4 + 2] = ss2; ssq[w][L * 4 + 3] = ss3;
    }
    __syncthreads();   // all waves done with stage -> reuse as red

    float asl = 0.f;
    #pragma unroll
    for (int ph = 0; ph < 2; ++ph) {
        // write this n-half's partials
        {
            float* rp = red + w * (16 * 68);
            #pragma unroll
            for (int mt = 0; mt < 4; ++mt)
                *reinterpret_cast<f32x4*>(&rp[lid * 68 + mt * 16 + quad * 4]) = acc[mt][ph];
        }
        __syncthreads();
        // softmax: wave w handles local rows ph*16 + w*4 .. +3; lane L = k
        float vv[4], iv[4];
        #pragma unroll
        for (int i = 0; i < 4; ++i) {
            int nl = ph * 16 + w * 4 + i;
            float s = ssq[0][nl] + ssq[1][nl] + ssq[2][nl] + ssq[3][nl];
            iv[i] = 1.0f / fmaxf(sqrtf(s), EPSV);
            int nr = w * 4 + i;   // row slot within red
            float v = red[0 * 1088 + nr * 68 + L] + red[1 * 1088 + nr * 68 + L]
                    + red[2 * 1088 + nr * 68 + L] + red[3 * 1088 + nr * 68 + L];
            vv[i] = fmaf(v, iv[i], bk);
        }
        float mx[4] = {vv[0], vv[1], vv[2], vv[3]};
        #pragma unroll
        for (int m = 1; m <= 32; m <<= 1) {
            #pragma unroll
            for (int i = 0; i < 4; ++i) mx[i] = fmaxf(mx[i], __shfl_xor(mx[i], m, 64));
        }
        float e[4], se[4];
        #pragma unroll
        for (int i = 0; i < 4; ++i) { e[i] = __expf(vv[i] - mx[i]); se[i] = e[i]; }
        #pragma unroll
        for (int m = 1; m <= 32; m <<= 1) {
            #pragma unroll
            for (int i = 0; i < 4; ++i) se[i] += __shfl_xor(se[i], m, 64);
        }
        unsigned short av[4];
        #pragma unroll
        for (int i = 0; i < 4; ++i) {
            bool valid = (n0 + ph * 16 + w * 4 + i) < N_;  // block 24 ph=1: tail zeros
            float a = e[i] / se[i];
            av[i] = valid ? f2bf(a * iv[i]) : (unsigned short)0;
            asl += valid ? a : 0.f;
        }
        ushort4 st; st.x = av[0]; st.y = av[1]; st.z = av[2]; st.w = av[3];
        *reinterpret_cast<ushort4*>(
            aT + ((size_t)t * 64 + L) * NA_ + n0 + ph * 16 + w * 4) = st;
        if (ph == 0) __syncthreads();   // red reads done before phase-B writes
    }
    atomicAdd(&asum[t * 64 + L], asl);
}

// vlad[t][k][c] = sum_n ahat[k][n]*x[c][n] - asum[k]*cent[k][c]; g2 partial fused.
// split over k-halves (grid 32 x 2 x 30 = 1920 blocks, 7.5/CU):
// disjoint vlad stores (no atomics), per-block 2 MFMA tiles; x fp32 (L3-hot).
__global__ __launch_bounds__(256, 4) void k_vlad(
    const float* __restrict__ x, const unsigned short* __restrict__ aT,
    const float* __restrict__ asum, const float* __restrict__ cent,
    float* __restrict__ vlad, float* __restrict__ g2)
{
    __shared__ float red[4][16 * 36];   // [wave][c(16) x k(32)+pad4]
    int t = blockIdx.z, kh = blockIdx.y, c0 = blockIdx.x * 16;
    int tid = threadIdx.x;
    int w = tid >> 6, L = tid & 63, lid = L & 15, quad = L >> 4;

    f32x4 acc[2];
    #pragma unroll
    for (int mt = 0; mt < 2; ++mt)
        #pragma unroll
        for (int r = 0; r < 4; ++r) acc[mt][r] = 0.f;

    const float* xrow = x + ((size_t)t * C_ + c0 + lid) * N_;
    const unsigned short* a0 = aT + ((size_t)t * 64 + kh * 32 + lid) * NA_;

    // epilogue operands issued early: thread -> (k_loc, 2 c's)
    int k_loc = tid >> 3, j8 = tid & 7, ce = j8 * 2;
    int kg = kh * 32 + k_loc;
    float as = asum[t * 64 + kg];
    float2 cv = *reinterpret_cast<const float2*>(cent + kg * C_ + c0 + ce);

    // prologue: load step s0 = w
    int nb = w * 32 + quad * 8;
    int nc = nb > 776 ? 776 : nb;   // clamped lanes hit aT zeros
    float4 x0c = *reinterpret_cast<const float4*>(xrow + nc);
    float4 x1c = *reinterpret_cast<const float4*>(xrow + nc + 4);
    bf16x8 f0 = *reinterpret_cast<const bf16x8*>(a0 + nb);
    bf16x8 f1 = *reinterpret_cast<const bf16x8*>(a0 + 16 * NA_ + nb);

    for (int s = w; s < 25; s += 4) {
        int sn = s + 4;
        float4 x0n = x0c, x1n = x1c;
        bf16x8 g0 = f0, g1 = f1;
        if (sn < 25) {  // wave-uniform: prefetch next step
            int nb2 = sn * 32 + quad * 8;
            int nc2 = nb2 > 776 ? 776 : nb2;
            x0n = *reinterpret_cast<const float4*>(xrow + nc2);
            x1n = *reinterpret_cast<const float4*>(xrow + nc2 + 4);
            g0  = *reinterpret_cast<const bf16x8*>(a0 + nb2);
            g1  = *reinterpret_cast<const bf16x8*>(a0 + 16 * NA_ + nb2);
        }
        bf16x8 bb;
        bb[0] = (short)f2bf(x0c.x); bb[1] = (short)f2bf(x0c.y);
        bb[2] = (short)f2bf(x0c.z); bb[3] = (short)f2bf(x0c.w);
        bb[4] = (short)f2bf(x1c.x); bb[5] = (short)f2bf(x1c.y);
        bb[6] = (short)f2bf(x1c.z); bb[7] = (short)f2bf(x1c.w);
        acc[0] = __builtin_amdgcn_mfma_f32_16x16x32_bf16(f0, bb, acc[0], 0, 0, 0);
        acc[1] = __builtin_amdgcn_mfma_f32_16x16x32_bf16(f1, bb, acc[1], 0, 0, 0);
        x0c = x0n; x1c = x1n; f0 = g0; f1 = g1;
    }
    {
        float* rp = &red[w][0];
        #pragma unroll
        for (int mt = 0; mt < 2; ++mt)
            *reinterpret_cast<f32x4*>(&rp[lid * 36 + mt * 16 + quad * 4]) = acc[mt];
    }
    __syncthreads();

    // epilogue: v for (kg, ce..ce+1); fused g2 partial
    float2 vout;
    float s2 = 0.f;
    #pragma unroll
    for (int j = 0; j < 2; ++j) {
        int cc = ce + j;
        float v = red[0][cc * 36 + k_loc] + red[1][cc * 36 + k_loc]
                + red[2][cc * 36 + k_loc] + red[3][cc * 36 + k_loc];
        v -= as * ((const float*)&cv)[j];
        ((float*)&vout)[j] = v;
        s2 = fmaf(v, v, s2);
    }
    *reinterpret_cast<float2*>(vlad + ((size_t)t * 64 + kg) * C_ + c0 + ce) = vout;
    s2 += __shfl_xor(s2, 1, 64);
    s2 += __shfl_xor(s2, 2, 64);
    s2 += __shfl_xor(s2, 4, 64);
    if (j8 == 0) atomicAdd(&g2[t * 64 + kg], s2);
}

// out[k*512+c] = sum_t vlad * inv_intra * inv_g. t split over 2 thread-halves
// (grid 256 blocks, 128 idx each) for 2x parallelism + half-depth load chains.
__global__ __launch_bounds__(256) void k_out(
    const float* __restrict__ vlad, const float* __restrict__ g2,
    float* __restrict__ out)
{
    __shared__ float intr[1920];
    __shared__ float gl[1920];
    __shared__ float sinv[T_];
    __shared__ float part[256];
    int tid = threadIdx.x;
    for (int i = tid; i < 1920; i += 256) {
        float s = g2[i];
        gl[i] = s;
        intr[i] = 1.0f / fmaxf(sqrtf(s), EPSV);
    }
    __syncthreads();
    if (tid < T_) {
        float s = 0.f;
        #pragma unroll 8
        for (int k = 0; k < 64; ++k) {
            float iv = intr[tid * 64 + k];
            s += gl[tid * 64 + k] * iv * iv;
        }
        sinv[tid] = 1.0f / fmaxf(sqrtf(s), EPSV);
    }
    __syncthreads();
    int idx = blockIdx.x * 128 + (tid & 127);  // k*512+c
    int th = tid >> 7;
    int k = idx >> 9;
    float s = 0.f;
    #pragma unroll
    for (int t = th * 15; t < th * 15 + 15; ++t)
        s += vlad[(size_t)t * 32768 + idx] * intr[t * 64 + k] * sinv[t];
    part[tid] = s;
    __syncthreads();
    if (tid < 128) out[idx] = part[tid] + part[tid + 128];
}

extern "C" void kernel_launch(void* const* d_in, const int* in_sizes, int n_in,
                              void* d_out, int out_size, void* d_ws, size_t ws_size,
                              hipStream_t stream) {
    const float* x    = (const float*)d_in[0];   // 30*512*784
    const float* cent = (const float*)d_in[1];   // 64*512
    const float* w    = (const float*)d_in[2];   // 64*512
    const float* b    = (const float*)d_in[3];   // 64
    float* out = (float*)d_out;

    char* p = (char*)d_ws;
    unsigned short* wh = (unsigned short*)p;  p += 65536;
    unsigned short* wl = (unsigned short*)p;  p += 65536;
    float* asum = (float*)p;                  p += 1920 * 4;
    float* g2   = (float*)p;                  p += 1920 * 4;
    float* vlad = (float*)p;                  p += (size_t)T_ * 64 * C_ * 4;   // 3,932,160
    unsigned short* aT = (unsigned short*)p;  p += (size_t)T_ * 64 * NA_ * 2;  // 3,072,000
    // total ~= 7.2 MB

    k_prep<<<128, 256, 0, stream>>>(w, wh, wl);
    hipMemsetAsync(asum, 0, 2 * 1920 * 4, stream);   // asum + g2 (15 KB only)
    k_assign<<<dim3(25, T_), 256, 0, stream>>>(x, wh, wl, b, aT, asum);
    k_vlad<<<dim3(32, 2, T_), 256, 0, stream>>>(x, aT, asum, cent, vlad, g2);
    k_out<<<256, 256, 0, stream>>>(vlad, g2, out);
}